// Round 2
// baseline (233.268 us; speedup 1.0000x reference)
//
#include <hip/hip_runtime.h>
#include <hip/hip_bf16.h>

typedef __bf16 bf16x8 __attribute__((ext_vector_type(8)));
typedef float  f32x4  __attribute__((ext_vector_type(4)));
typedef short  s16x8  __attribute__((ext_vector_type(8)));
typedef unsigned short u16;

// round-to-nearest-even fp32 -> bf16 (as u16 bits)
static __device__ __forceinline__ u16 f2bf_rne(float f) {
  union { float f; unsigned u; } x; x.f = f;
  unsigned r = x.u + 0x7fffu + ((x.u >> 16) & 1u);
  return (u16)(r >> 16);
}

// split fp32 into bf16 hi (truncated) + bf16 lo (exact residual, truncated)
static __device__ __forceinline__ void splitbf(float f, short& hi, short& lo) {
  union { float f; unsigned u; } x; x.f = f;
  hi = (short)(x.u >> 16);
  union { unsigned u; float f; } h; h.u = x.u & 0xffff0000u;
  union { float f; unsigned u; } y; y.f = f - h.f;   // exact (Sterbenz)
  lo = (short)(y.u >> 16);
}

// async global->LDS, 16B/lane; LDS dest = uniform base + lane*16 (linear).
#define GLD_LDS16(g, l)                                                        \
  __builtin_amdgcn_global_load_lds(                                            \
      (const __attribute__((address_space(1))) void*)(g),                      \
      (__attribute__((address_space(3))) void*)(l), 16, 0, 0)

// Persistent pipeline: 512 blocks x 512 threads (8 waves), 8 rows per block,
// 2 rows per iteration (waves 0-3 -> row A, waves 4-7 -> row B; each wave =
// one 16-wide d-slice, exactly the round-1 per-wave job).
//
// T3/T4 structure: double-buffered Q/K staging (2 x 64KB LDS). Loads for
// iteration t+1 are issued right after iteration t's top barrier, so the
// vmcnt(0) that guards them executes a FULL compute-phase later (steady-state
// free). Mid-iteration barrier is a raw s_barrier (no vmcnt drain) so the
// prefetch stays in flight across it. V bypasses LDS entirely: its A-fragment
// pattern from global is 128B-coalesced, loaded to registers one iteration
// ahead.
__global__ __launch_bounds__(512, 2)
void attn64_kernel(const float* __restrict__ q, const float* __restrict__ k,
                   const float* __restrict__ v, float* __restrict__ out)
{
  // [dbuf][qk][row][4096 floats] = 128 KB
  __shared__ float lds[2][2][2][4096];

  const int tid  = threadIdx.x;
  const int wid  = tid >> 6;        // 0..7
  const int lane = tid & 63;
  const int quad = lane >> 4;
  const int lo   = lane & 15;
  const int rw   = wid >> 2;        // which row of the pair this wave computes
  const int wq   = wid & 3;         // d-slice index within the row
  const int rowBase = blockIdx.x * 8;

  // ---- stage(t,b): issue 8 GLD_LDS (this wave's 8 of 64 1KB chunks).
  // chunk c = wid*8+i; sec=c>>4: {Q row0, K row0, Q row1, K row1}; c4=c&15
  // covers h-rows [4c4, 4c4+4). Swizzle e' = e ^ (((h>>3)&1)<<4) on the
  // global source (LDS dest is linear).
  auto stage = [&](int t, int b) {
    const int hl = lane >> 4;
    const int e4 = (lane & 15) << 2;
#pragma unroll
    for (int i = 0; i < 8; ++i) {
      const int c   = wid * 8 + i;
      const int sec = c >> 4;
      const int c4  = c & 15;
      const int h   = c4 * 4 + hl;
      const int se  = e4 ^ (((h >> 3) & 1) << 4);
      const float* src = ((sec & 1) ? k : q)
                       + (size_t)(rowBase + t * 2 + (sec >> 1)) * 4096
                       + h * 64 + se;
      GLD_LDS16(src, &lds[b][sec & 1][sec >> 1][c4 * 256]);
    }
  };

  // ---- V for this wave's row, straight to registers (128B-coalesced):
  // frag [ks*4+mt] = V[h=lo+16mt][e=quad*8+ks*32 .. +7]
  f32x4 xv[8][2];
  auto loadV = [&](int t) {
    const float* vrow = v + (size_t)(rowBase + t * 2 + rw) * 4096;
#pragma unroll
    for (int ks = 0; ks < 2; ++ks)
#pragma unroll
      for (int mt = 0; mt < 4; ++mt) {
        const float* p = vrow + (lo + 16 * mt) * 64 + quad * 8 + ks * 32;
        xv[ks * 4 + mt][0] = *(const f32x4*)p;
        xv[ks * 4 + mt][1] = *(const f32x4*)(p + 4);
      }
  };

  // ---- prologue: fill pipe for iteration 0
  stage(0, 0);
  loadV(0);

  for (int t = 0; t < 4; ++t) {
    const int b = t & 1;

    // B1: all prefetched loads (issued one full iteration ago) must be done;
    // barrier also guarantees every wave finished reading buf[b^1] so it can
    // be overwritten. Single asm keeps waitcnt->barrier order fixed.
    asm volatile("s_waitcnt vmcnt(0)\n\ts_barrier" ::: "memory");
    __builtin_amdgcn_sched_barrier(0);

    // convert this iteration's V (loads already drained -> free)
    bf16x8 av[8];
#pragma unroll
    for (int i = 0; i < 8; ++i) {
      s16x8 tv;
#pragma unroll
      for (int j = 0; j < 4; ++j) {
        tv[j]     = (short)f2bf_rne(xv[i][0][j]);
        tv[4 + j] = (short)f2bf_rne(xv[i][1][j]);
      }
      av[i] = __builtin_bit_cast(bf16x8, tv);
    }

    // issue NEXT iteration's loads now; they stay in flight across the whole
    // compute phase and the mid-iteration raw barrier.
    if (t < 3) {
      stage(t + 1, b ^ 1);
      loadV(t + 1);
    }

    const float* ldsQ = &lds[b][0][rw][0];
    float*       ldsK = &lds[b][1][rw][0];   // overlaid by P after B2

    // ---- Q A-frags: A[m=d=wq*16+lo][k=h=ks*32+quad*8+j], hi/lo split
    s16x8 qh[2], ql[2];
    {
      const int dcol = wq * 16 + lo;
#pragma unroll
      for (int ks = 0; ks < 2; ++ks)
#pragma unroll
        for (int j = 0; j < 8; ++j) {
          const int h = ks * 32 + quad * 8 + j;
          float x = ldsQ[h * 64 + (dcol ^ ((quad & 1) << 4))];
          short hh, ll; splitbf(x, hh, ll);
          qh[ks][j] = hh; ql[ks][j] = ll;
        }
    }

    // ---- Matmul 1: S[d][e] = sum_h Q[h][d] K[h][e].  24 MFMAs/wave.
    f32x4 acc[4];
#pragma unroll
    for (int et = 0; et < 4; ++et) acc[et] = (f32x4){0.f, 0.f, 0.f, 0.f};

#pragma unroll
    for (int et = 0; et < 4; ++et)
#pragma unroll
      for (int ks = 0; ks < 2; ++ks) {
        s16x8 kh, kl;
#pragma unroll
        for (int j = 0; j < 8; ++j) {
          const int h = ks * 32 + quad * 8 + j;
          float x = ldsK[h * 64 + ((lo + 16 * et) ^ ((quad & 1) << 4))];
          short hh, ll; splitbf(x, hh, ll);
          kh[j] = hh; kl[j] = ll;
        }
        bf16x8 ah = __builtin_bit_cast(bf16x8, qh[ks]);
        bf16x8 al = __builtin_bit_cast(bf16x8, ql[ks]);
        bf16x8 bh = __builtin_bit_cast(bf16x8, kh);
        bf16x8 bl = __builtin_bit_cast(bf16x8, kl);
        acc[et] = __builtin_amdgcn_mfma_f32_16x16x32_bf16(ah, bh, acc[et], 0, 0, 0);
        acc[et] = __builtin_amdgcn_mfma_f32_16x16x32_bf16(ah, bl, acc[et], 0, 0, 0);
        acc[et] = __builtin_amdgcn_mfma_f32_16x16x32_bf16(al, bh, acc[et], 0, 0, 0);
      }

    // ---- Softmax over e per row d. acc[et][r] = S[wq*16+quad*4+r][16et+lo]
#pragma unroll
    for (int r = 0; r < 4; ++r) {
      float m = fmaxf(fmaxf(acc[0][r], acc[1][r]), fmaxf(acc[2][r], acc[3][r]));
#pragma unroll
      for (int off = 1; off < 16; off <<= 1) m = fmaxf(m, __shfl_xor(m, off));
      float s = 0.f;
#pragma unroll
      for (int et = 0; et < 4; ++et) {
        float e0 = __expf(acc[et][r] - m);
        acc[et][r] = e0;
        s += e0;
      }
#pragma unroll
      for (int off = 1; off < 16; off <<= 1) s += __shfl_xor(s, off);
      float rs = 1.0f / s;
#pragma unroll
      for (int et = 0; et < 4; ++et) acc[et][r] *= rs;
    }

    // B2: raw barrier (NO vmcnt drain -> prefetch stays in flight). All
    // row-waves have consumed K (values already in registers) -> safe to
    // overlay P on the K region.
    asm volatile("s_barrier" ::: "memory");
    __builtin_amdgcn_sched_barrier(0);

    // ---- P -> LDS (f32, swizzled idx = d*64 + (e ^ ((d&15)<<2))).
    // Each wave re-reads only its own d-slice -> within-wave DS ordering.
    float* P = ldsK;
#pragma unroll
    for (int r = 0; r < 4; ++r) {
      const int d   = wq * 16 + quad * 4 + r;
      const int swz = (d & 15) << 2;
#pragma unroll
      for (int et = 0; et < 4; ++et)
        P[d * 64 + ((lo + 16 * et) ^ swz)] = acc[et][r];
    }

    // ---- Matmul 2: Out[h][d] = sum_e V[h][e] P[d][e].  8 MFMAs/wave.
    f32x4 acc2[4];
#pragma unroll
    for (int mt = 0; mt < 4; ++mt) acc2[mt] = (f32x4){0.f, 0.f, 0.f, 0.f};

#pragma unroll
    for (int ks = 0; ks < 2; ++ks) {
      const int eb    = quad * 8 + ks * 32;
      const int dmine = wq * 16 + lo;
      const int pswz  = lo << 2;          // (dmine&15)<<2
      f32x4 p0 = *(const f32x4*)&P[dmine * 64 + (eb ^ pswz)];
      f32x4 p1 = *(const f32x4*)&P[dmine * 64 + ((eb + 4) ^ pswz)];
      s16x8 tp;
#pragma unroll
      for (int j = 0; j < 4; ++j) {
        tp[j]     = (short)f2bf_rne(p0[j]);
        tp[4 + j] = (short)f2bf_rne(p1[j]);
      }
      bf16x8 bp = __builtin_bit_cast(bf16x8, tp);
#pragma unroll
      for (int mt = 0; mt < 4; ++mt)
        acc2[mt] = __builtin_amdgcn_mfma_f32_16x16x32_bf16(av[ks * 4 + mt], bp, acc2[mt], 0, 0, 0);
    }

    // ---- Store fp32: out[h*64+d], h = 16mt+quad*4+r, d = wq*16+lo.
    float* orow = out + (size_t)(rowBase + t * 2 + rw) * 4096;
#pragma unroll
    for (int mt = 0; mt < 4; ++mt)
#pragma unroll
      for (int r = 0; r < 4; ++r) {
        const int h = 16 * mt + quad * 4 + r;
        orow[h * 64 + wq * 16 + lo] = acc2[mt][r];
      }
  }
}

extern "C" void kernel_launch(void* const* d_in, const int* in_sizes, int n_in,
                              void* d_out, int out_size, void* d_ws, size_t ws_size,
                              hipStream_t stream) {
  const float* q = (const float*)d_in[0];
  const float* k = (const float*)d_in[1];
  const float* v = (const float*)d_in[2];
  float* o = (float*)d_out;
  hipLaunchKernelGGL(attn64_kernel, dim3(512), dim3(512), 0, stream, q, k, v, o);
}

// Round 3
// 215.572 us; speedup vs baseline: 1.0821x; 1.0821x over previous
//
#include <hip/hip_runtime.h>
#include <hip/hip_bf16.h>

typedef __bf16 bf16x8 __attribute__((ext_vector_type(8)));
typedef float  f32x4  __attribute__((ext_vector_type(4)));
typedef short  s16x8  __attribute__((ext_vector_type(8)));
typedef unsigned short u16;

// round-to-nearest-even fp32 -> bf16 (as u16 bits)
static __device__ __forceinline__ u16 f2bf_rne(float f) {
  union { float f; unsigned u; } x; x.f = f;
  unsigned r = x.u + 0x7fffu + ((x.u >> 16) & 1u);
  return (u16)(r >> 16);
}

// split fp32 into bf16 hi (truncated) + bf16 lo (exact residual, truncated)
static __device__ __forceinline__ void splitbf(float f, short& hi, short& lo) {
  union { float f; unsigned u; } x; x.f = f;
  hi = (short)(x.u >> 16);
  union { unsigned u; float f; } h; h.u = x.u & 0xffff0000u;
  union { float f; unsigned u; } y; y.f = f - h.f;   // exact (Sterbenz)
  lo = (short)(y.u >> 16);
}

// async global->LDS, 16B/lane; LDS dest = uniform base + lane*16 (linear),
// so all layout swizzling is applied on the per-lane GLOBAL source address.
#define GLD_LDS16(g, l)                                                        \
  __builtin_amdgcn_global_load_lds(                                            \
      (const __attribute__((address_space(1))) void*)(g),                      \
      (__attribute__((address_space(3))) void*)(l), 16, 0, 0)

// One row per 4-wave block; wave w owns d-slice [16w,16w+16). Occupancy is
// the designed-for lever (round 0-2 all plateaued at ~4-5 B/cyc/CU from
// too few resident blocks): LDS cut to 32KB (Q,K only) and VGPR capped at
// 128 via launch_bounds(256,4) -> 4 independent blocks/CU (16 waves), so
// some block always has loads in flight while others drain/compute.
// V never touches LDS: its MFMA A-frag pattern from global is 64B-segment
// coalesced; issued right after barrier 1 so its latency hides under
// matmul1 + softmax.
//
// Swizzle (float-index within a 64-float h-row, applied on staging source):
//   Q,K : e' = e ^ (((h>>3)&1)<<4)
//   P   : idx = d*64 + (e ^ ((d&15)<<2)), f32, overlays ldsK (dead after mm1)
__global__ __launch_bounds__(256, 4)
void attn64_kernel(const float* __restrict__ q, const float* __restrict__ k,
                   const float* __restrict__ v, float* __restrict__ out)
{
  __shared__ float ldsQ[4096];
  __shared__ float ldsK[4096];   // reused as swizzled f32 P after matmul1

  const int tid  = threadIdx.x;
  const int wid  = tid >> 6;
  const int lane = tid & 63;
  const int quad = lane >> 4;
  const int lo   = lane & 15;
  const int row  = blockIdx.x;

  const float* qrow = q + (size_t)row * 4096;
  const float* krow = k + (size_t)row * 4096;
  const float* vrow = v + (size_t)row * 4096;
  float*       orow = out + (size_t)row * 4096;

  // ---- Stage Q,K: 32 chunks of 1KB (4 h-rows each); wave w takes chunks
  // [8w, 8w+8). Per-lane source addr carries the swizzle; LDS dest linear.
  {
    const int hl = lane >> 4;          // h-row within chunk
    const int e4 = (lane & 15) << 2;   // 4-float slot within row
#pragma unroll
    for (int i = 0; i < 8; ++i) {
      const int c   = wid * 8 + i;     // 0..31
      const int sec = c >> 4;          // 0 = Q, 1 = K
      const int c4  = c & 15;
      const int h   = c4 * 4 + hl;
      const int se  = e4 ^ (((h >> 3) & 1) << 4);
      const float* src = (sec ? krow : qrow) + h * 64 + se;
      GLD_LDS16(src, (sec ? ldsK : ldsQ) + c4 * 256);
    }
  }
  __syncthreads();   // drains vmcnt(0): Q,K resident

  // ---- Issue V now (consumed after softmax; latency hides under mm1):
  // frag [ks*4+mt] = V[h=lo+16mt][e=quad*8+ks*32 .. +7], 64B segments.
  f32x4 xv[8][2];
#pragma unroll
  for (int ks = 0; ks < 2; ++ks)
#pragma unroll
    for (int mt = 0; mt < 4; ++mt) {
      const float* p = vrow + (lo + 16 * mt) * 64 + quad * 8 + ks * 32;
      xv[ks * 4 + mt][0] = *(const f32x4*)p;
      xv[ks * 4 + mt][1] = *(const f32x4*)(p + 4);
    }
  __builtin_amdgcn_sched_barrier(0);   // keep the V issue ahead of compute

  // ---- Q A-frags: A[m=d=wid*16+lo][k=h=ks*32+quad*8+j], hi/lo split.
  s16x8 qh[2], ql[2];
  {
    const int dcol = wid * 16 + lo;
#pragma unroll
    for (int ks = 0; ks < 2; ++ks)
#pragma unroll
      for (int j = 0; j < 8; ++j) {
        const int h = ks * 32 + quad * 8 + j;
        float x = ldsQ[h * 64 + (dcol ^ ((quad & 1) << 4))];
        short hh, ll; splitbf(x, hh, ll);
        qh[ks][j] = hh; ql[ks][j] = ll;
      }
  }

  // ---- Matmul 1: S[dslice][e] = sum_h Q[h][d] K[h][e].  24 MFMAs/wave.
  f32x4 acc[4];
#pragma unroll
  for (int et = 0; et < 4; ++et) acc[et] = (f32x4){0.f, 0.f, 0.f, 0.f};

#pragma unroll
  for (int et = 0; et < 4; ++et)
#pragma unroll
    for (int ks = 0; ks < 2; ++ks) {
      s16x8 kh, kl;
#pragma unroll
      for (int j = 0; j < 8; ++j) {
        const int h = ks * 32 + quad * 8 + j;
        float x = ldsK[h * 64 + ((lo + 16 * et) ^ ((quad & 1) << 4))];
        short hh, ll; splitbf(x, hh, ll);
        kh[j] = hh; kl[j] = ll;
      }
      bf16x8 ah = __builtin_bit_cast(bf16x8, qh[ks]);
      bf16x8 al = __builtin_bit_cast(bf16x8, ql[ks]);
      bf16x8 bh = __builtin_bit_cast(bf16x8, kh);
      bf16x8 bl = __builtin_bit_cast(bf16x8, kl);
      acc[et] = __builtin_amdgcn_mfma_f32_16x16x32_bf16(ah, bh, acc[et], 0, 0, 0);
      acc[et] = __builtin_amdgcn_mfma_f32_16x16x32_bf16(ah, bl, acc[et], 0, 0, 0);
      acc[et] = __builtin_amdgcn_mfma_f32_16x16x32_bf16(al, bh, acc[et], 0, 0, 0);
    }

  // ---- Softmax over e per row d. acc[et][r] = S[wid*16+quad*4+r][16et+lo];
  // each quad owns 4 rows, reduce across its 16 lanes.
#pragma unroll
  for (int r = 0; r < 4; ++r) {
    float m = fmaxf(fmaxf(acc[0][r], acc[1][r]), fmaxf(acc[2][r], acc[3][r]));
#pragma unroll
    for (int off = 1; off < 16; off <<= 1) m = fmaxf(m, __shfl_xor(m, off));
    float s = 0.f;
#pragma unroll
    for (int et = 0; et < 4; ++et) {
      float e0 = __expf(acc[et][r] - m);
      acc[et][r] = e0;
      s += e0;
    }
#pragma unroll
    for (int off = 1; off < 16; off <<= 1) s += __shfl_xor(s, off);
    float rs = 1.0f / s;
#pragma unroll
    for (int et = 0; et < 4; ++et) acc[et][r] *= rs;
  }

  __syncthreads();   // all waves done reading K -> safe to overlay P on ldsK
                     // (also drains V loads, issued ~3K cyc ago -> free)

  // ---- Convert V (long since landed).
  bf16x8 av[8];
#pragma unroll
  for (int i = 0; i < 8; ++i) {
    s16x8 tv;
#pragma unroll
    for (int j = 0; j < 4; ++j) {
      tv[j]     = (short)f2bf_rne(xv[i][0][j]);
      tv[4 + j] = (short)f2bf_rne(xv[i][1][j]);
    }
    av[i] = __builtin_bit_cast(bf16x8, tv);
  }

  // ---- P -> LDS (f32, swizzled idx = d*64 + (e ^ ((d&15)<<2))).
  // Each wave re-reads only its own d-slice -> within-wave DS ordering.
  float* P = ldsK;
#pragma unroll
  for (int r = 0; r < 4; ++r) {
    const int d   = wid * 16 + quad * 4 + r;
    const int swz = (d & 15) << 2;
#pragma unroll
    for (int et = 0; et < 4; ++et)
      P[d * 64 + ((lo + 16 * et) ^ swz)] = acc[et][r];
  }

  // ---- Matmul 2: Out[h][d] = sum_e V[h][e] P[d][e].  8 MFMAs/wave.
  f32x4 acc2[4];
#pragma unroll
  for (int mt = 0; mt < 4; ++mt) acc2[mt] = (f32x4){0.f, 0.f, 0.f, 0.f};

#pragma unroll
  for (int ks = 0; ks < 2; ++ks) {
    const int eb    = quad * 8 + ks * 32;
    const int dmine = wid * 16 + lo;
    const int pswz  = lo << 2;            // (dmine&15)<<2
    f32x4 p0 = *(const f32x4*)&P[dmine * 64 + (eb ^ pswz)];
    f32x4 p1 = *(const f32x4*)&P[dmine * 64 + ((eb + 4) ^ pswz)];
    s16x8 tp;
#pragma unroll
    for (int j = 0; j < 4; ++j) {
      tp[j]     = (short)f2bf_rne(p0[j]);
      tp[4 + j] = (short)f2bf_rne(p1[j]);
    }
    bf16x8 bp = __builtin_bit_cast(bf16x8, tp);
#pragma unroll
    for (int mt = 0; mt < 4; ++mt)
      acc2[mt] = __builtin_amdgcn_mfma_f32_16x16x32_bf16(av[ks * 4 + mt], bp, acc2[mt], 0, 0, 0);
  }

  // ---- Store fp32: out[h*64+d], h = 16mt+quad*4+r, d = wid*16+lo.
#pragma unroll
  for (int mt = 0; mt < 4; ++mt)
#pragma unroll
    for (int r = 0; r < 4; ++r) {
      const int h = 16 * mt + quad * 4 + r;
      orow[h * 64 + wid * 16 + lo] = acc2[mt][r];
    }
}

extern "C" void kernel_launch(void* const* d_in, const int* in_sizes, int n_in,
                              void* d_out, int out_size, void* d_ws, size_t ws_size,
                              hipStream_t stream) {
  const float* q = (const float*)d_in[0];
  const float* k = (const float*)d_in[1];
  const float* v = (const float*)d_in[2];
  float* o = (float*)d_out;
  hipLaunchKernelGGL(attn64_kernel, dim3(4096), dim3(256), 0, stream, q, k, v, o);
}

// Round 4
// 214.454 us; speedup vs baseline: 1.0877x; 1.0052x over previous
//
#include <hip/hip_runtime.h>
#include <hip/hip_bf16.h>

typedef __bf16 bf16x8 __attribute__((ext_vector_type(8)));
typedef float  f32x4  __attribute__((ext_vector_type(4)));
typedef short  s16x8  __attribute__((ext_vector_type(8)));
typedef unsigned short u16;

// round-to-nearest-even fp32 -> bf16 (as u16 bits)
static __device__ __forceinline__ u16 f2bf_rne(float f) {
  union { float f; unsigned u; } x; x.f = f;
  unsigned r = x.u + 0x7fffu + ((x.u >> 16) & 1u);
  return (u16)(r >> 16);
}

// split fp32 into bf16 hi (truncated) + bf16 lo (exact residual, truncated)
static __device__ __forceinline__ void splitbf(float f, short& hi, short& lo) {
  union { float f; unsigned u; } x; x.f = f;
  hi = (short)(x.u >> 16);
  union { unsigned u; float f; } h; h.u = x.u & 0xffff0000u;
  union { float f; unsigned u; } y; y.f = f - h.f;   // exact (Sterbenz)
  lo = (short)(y.u >> 16);
}

// async global->LDS, 16B/lane; LDS dest = uniform base + lane*16 (linear),
// so all layout swizzling is applied on the per-lane GLOBAL source address.
#define GLD_LDS16(g, l)                                                        \
  __builtin_amdgcn_global_load_lds(                                            \
      (const __attribute__((address_space(1))) void*)(g),                      \
      (__attribute__((address_space(3))) void*)(l), 16, 0, 0)

// One row per 4-wave block. mm1/softmax: wave w owns d-slice [16w,16w+16).
// mm2 is split by H instead of d: wave w computes Out rows h in [16w,16w+16)
// for ALL d. This makes each wave's V A-fragment exactly its own 16 h-rows:
// 4 f32x4 loads/lane, 16KB per block total -- the round-3 version loaded the
// WHOLE 16KB V row in every wave (4x duplication, 64KB/block), which per the
// cross-round arithmetic (~5.5-6 B/cyc/CU of serviced requests in rounds
// 1-3) was the largest demanded-traffic stream. P lives in LDS and is shared,
// so mm2's cross-wave P reads are cheap; one extra barrier makes them safe.
//
// Swizzle (float-index within a 64-float h-row, applied on staging source):
//   Q,K : e' = e ^ (((h>>3)&1)<<4)
//   P   : idx = d*64 + (e ^ ((d&15)<<2)), f32, overlays ldsK (dead after mm1)
__global__ __launch_bounds__(256, 4)
void attn64_kernel(const float* __restrict__ q, const float* __restrict__ k,
                   const float* __restrict__ v, float* __restrict__ out)
{
  __shared__ float ldsQ[4096];
  __shared__ float ldsK[4096];   // reused as swizzled f32 P after matmul1

  const int tid  = threadIdx.x;
  const int wid  = tid >> 6;
  const int lane = tid & 63;
  const int quad = lane >> 4;
  const int lo   = lane & 15;
  const int row  = blockIdx.x;

  const float* qrow = q + (size_t)row * 4096;
  const float* krow = k + (size_t)row * 4096;
  const float* vrow = v + (size_t)row * 4096;
  float*       orow = out + (size_t)row * 4096;

  // ---- Stage Q,K: 32 chunks of 1KB (4 h-rows each); wave w takes chunks
  // [8w, 8w+8). Per-lane source addr carries the swizzle; LDS dest linear.
  {
    const int hl = lane >> 4;          // h-row within chunk
    const int e4 = (lane & 15) << 2;   // 4-float slot within row
#pragma unroll
    for (int i = 0; i < 8; ++i) {
      const int c   = wid * 8 + i;     // 0..31
      const int sec = c >> 4;          // 0 = Q, 1 = K
      const int c4  = c & 15;
      const int h   = c4 * 4 + hl;
      const int se  = e4 ^ (((h >> 3) & 1) << 4);
      const float* src = (sec ? krow : qrow) + h * 64 + se;
      GLD_LDS16(src, (sec ? ldsK : ldsQ) + c4 * 256);
    }
  }
  __syncthreads();   // drains vmcnt(0): Q,K resident

  // ---- Issue V now (consumed in mm2, two barriers later): wave w needs only
  // its h-slice [16w,16w+16): A[m=h=16w+lo][k=e=quad*8+ks*32+j].
  // 4 f32x4 per lane, 16KB per BLOCK, no duplication.
  f32x4 xv[2][2];
#pragma unroll
  for (int ks = 0; ks < 2; ++ks) {
    const float* p = vrow + (wid * 16 + lo) * 64 + quad * 8 + ks * 32;
    xv[ks][0] = *(const f32x4*)p;
    xv[ks][1] = *(const f32x4*)(p + 4);
  }
  __builtin_amdgcn_sched_barrier(0);   // keep the V issue ahead of compute

  // ---- Q A-frags: A[m=d=wid*16+lo][k=h=ks*32+quad*8+j], hi/lo split.
  s16x8 qh[2], ql[2];
  {
    const int dcol = wid * 16 + lo;
#pragma unroll
    for (int ks = 0; ks < 2; ++ks)
#pragma unroll
      for (int j = 0; j < 8; ++j) {
        const int h = ks * 32 + quad * 8 + j;
        float x = ldsQ[h * 64 + (dcol ^ ((quad & 1) << 4))];
        short hh, ll; splitbf(x, hh, ll);
        qh[ks][j] = hh; ql[ks][j] = ll;
      }
  }

  // ---- Matmul 1: S[dslice][e] = sum_h Q[h][d] K[h][e].  24 MFMAs/wave.
  f32x4 acc[4];
#pragma unroll
  for (int et = 0; et < 4; ++et) acc[et] = (f32x4){0.f, 0.f, 0.f, 0.f};

#pragma unroll
  for (int et = 0; et < 4; ++et)
#pragma unroll
    for (int ks = 0; ks < 2; ++ks) {
      s16x8 kh, kl;
#pragma unroll
      for (int j = 0; j < 8; ++j) {
        const int h = ks * 32 + quad * 8 + j;
        float x = ldsK[h * 64 + ((lo + 16 * et) ^ ((quad & 1) << 4))];
        short hh, ll; splitbf(x, hh, ll);
        kh[j] = hh; kl[j] = ll;
      }
      bf16x8 ah = __builtin_bit_cast(bf16x8, qh[ks]);
      bf16x8 al = __builtin_bit_cast(bf16x8, ql[ks]);
      bf16x8 bh = __builtin_bit_cast(bf16x8, kh);
      bf16x8 bl = __builtin_bit_cast(bf16x8, kl);
      acc[et] = __builtin_amdgcn_mfma_f32_16x16x32_bf16(ah, bh, acc[et], 0, 0, 0);
      acc[et] = __builtin_amdgcn_mfma_f32_16x16x32_bf16(ah, bl, acc[et], 0, 0, 0);
      acc[et] = __builtin_amdgcn_mfma_f32_16x16x32_bf16(al, bh, acc[et], 0, 0, 0);
    }

  // ---- Softmax over e per row d. acc[et][r] = S[wid*16+quad*4+r][16et+lo];
  // each quad owns 4 rows, reduce across its 16 lanes.
#pragma unroll
  for (int r = 0; r < 4; ++r) {
    float m = fmaxf(fmaxf(acc[0][r], acc[1][r]), fmaxf(acc[2][r], acc[3][r]));
#pragma unroll
    for (int off = 1; off < 16; off <<= 1) m = fmaxf(m, __shfl_xor(m, off));
    float s = 0.f;
#pragma unroll
    for (int et = 0; et < 4; ++et) {
      float e0 = __expf(acc[et][r] - m);
      acc[et][r] = e0;
      s += e0;
    }
#pragma unroll
    for (int off = 1; off < 16; off <<= 1) s += __shfl_xor(s, off);
    float rs = 1.0f / s;
#pragma unroll
    for (int et = 0; et < 4; ++et) acc[et][r] *= rs;
  }

  __syncthreads();   // all waves done reading K -> safe to overlay P on ldsK

  // ---- P -> LDS (f32, swizzled idx = d*64 + (e ^ ((d&15)<<2))).
  float* P = ldsK;
#pragma unroll
  for (int r = 0; r < 4; ++r) {
    const int d   = wid * 16 + quad * 4 + r;
    const int swz = (d & 15) << 2;
#pragma unroll
    for (int et = 0; et < 4; ++et)
      P[d * 64 + ((lo + 16 * et) ^ swz)] = acc[et][r];
  }

  __syncthreads();   // P complete before cross-wave reads in mm2

  // ---- Convert V (loads issued two barriers ago -> long since landed).
  bf16x8 av[2];
#pragma unroll
  for (int ks = 0; ks < 2; ++ks) {
    s16x8 tv;
#pragma unroll
    for (int j = 0; j < 4; ++j) {
      tv[j]     = (short)f2bf_rne(xv[ks][0][j]);
      tv[4 + j] = (short)f2bf_rne(xv[ks][1][j]);
    }
    av[ks] = __builtin_bit_cast(bf16x8, tv);
  }

  // ---- Matmul 2: Out[h=16w..16w+16][d] = sum_e V[h][e] P[d][e].
  // B[k=e][n=d=16nt+lo] read from shared P; 8 MFMAs/wave.
  f32x4 acc2[4];
#pragma unroll
  for (int nt = 0; nt < 4; ++nt) acc2[nt] = (f32x4){0.f, 0.f, 0.f, 0.f};

#pragma unroll
  for (int ks = 0; ks < 2; ++ks) {
    const int eb = quad * 8 + ks * 32;
#pragma unroll
    for (int nt = 0; nt < 4; ++nt) {
      const int d    = nt * 16 + lo;
      const int pswz = lo << 2;           // (d&15)<<2
      f32x4 p0 = *(const f32x4*)&P[d * 64 + (eb ^ pswz)];
      f32x4 p1 = *(const f32x4*)&P[d * 64 + ((eb + 4) ^ pswz)];
      s16x8 tp;
#pragma unroll
      for (int j = 0; j < 4; ++j) {
        tp[j]     = (short)f2bf_rne(p0[j]);
        tp[4 + j] = (short)f2bf_rne(p1[j]);
      }
      bf16x8 bp = __builtin_bit_cast(bf16x8, tp);
      acc2[nt] = __builtin_amdgcn_mfma_f32_16x16x32_bf16(av[ks], bp, acc2[nt], 0, 0, 0);
    }
  }

  // ---- Store fp32: out[h*64+d], h = 16*wid+quad*4+r, d = lo+16nt.
#pragma unroll
  for (int nt = 0; nt < 4; ++nt)
#pragma unroll
    for (int r = 0; r < 4; ++r) {
      const int h = 16 * wid + quad * 4 + r;
      orow[h * 64 + lo + 16 * nt] = acc2[nt][r];
    }
}

extern "C" void kernel_launch(void* const* d_in, const int* in_sizes, int n_in,
                              void* d_out, int out_size, void* d_ws, size_t ws_size,
                              hipStream_t stream) {
  const float* q = (const float*)d_in[0];
  const float* k = (const float*)d_in[1];
  const float* v = (const float*)d_in[2];
  float* o = (float*)d_out;
  hipLaunchKernelGGL(attn64_kernel, dim3(4096), dim3(256), 0, stream, q, k, v, o);
}